// Round 12
// baseline (411.871 us; speedup 1.0000x reference)
//
#include <hip/hip_runtime.h>

// ---------------------------------------------------------------------------
// GAT (3 layers) + attention pooling + regressor.
// GEMMs: split-bf16 MFMA (a_hi+a_lo, 3 products, f32 accum), A staged in LDS
// via global_load_lds; attn scores fused into GEMM epilogue; h stored
// HEAD-MAJOR [H][N][64] (5.1MB/head gather set).
// CSR bucketed by (dst, src-quarter): aggregates walk src-quadrant runs in
// order -> concurrent waves' gather window ~1.3MB, fits per-XCD 4MB L2.
// N=20000 nodes, E=320000 edges (+N self loops), H=4 heads, C=64, B=16 graphs.
// ---------------------------------------------------------------------------

typedef unsigned short u16;
typedef __attribute__((ext_vector_type(8))) short bf16x8;
typedef __attribute__((ext_vector_type(4))) float f32x4;

__device__ __forceinline__ u16 bf16rn(float x) {
    unsigned u = __float_as_uint(x);
    u += 0x7FFFu + ((u >> 16) & 1u);
    return (u16)(u >> 16);
}
__device__ __forceinline__ float bf16f(u16 h) {
    return __uint_as_float(((unsigned)h) << 16);
}

__device__ __forceinline__ void gload16(const u16* g, u16* l) {
    __builtin_amdgcn_global_load_lds(
        (const __attribute__((address_space(1))) unsigned int*)g,
        (__attribute__((address_space(3))) unsigned int*)l, 16, 0, 0);
}

// ---------------- CSR build, bucketed by (dst, src-quarter) ----------------
__device__ __forceinline__ int quad_of(int s, int qs) {
    return (s >= qs) + (s >= 2 * qs) + (s >= 3 * qs);
}

__global__ void edge_hist_k(const int* __restrict__ ei, int E, int n, int qs,
                            int* __restrict__ deg) {
    int i = blockIdx.x * blockDim.x + threadIdx.x;
    if (i >= E + n) return;
    int src, dst;
    if (i < E) { src = ei[i]; dst = ei[E + i]; }
    else       { src = i - E; dst = src; }          // self-loop
    atomicAdd(&deg[dst * 4 + quad_of(src, qs)], 1);
}

__global__ __launch_bounds__(1024) void scan_excl_k(const int* __restrict__ deg, int* __restrict__ rowptr,
                                                    int* __restrict__ cursor, int n4) {
    __shared__ int part[1024];
    int tid = threadIdx.x;
    int chunk = (n4 + 1023) / 1024;
    int lo = tid * chunk;
    int hi = lo + chunk;
    if (lo > n4) lo = n4;
    if (hi > n4) hi = n4;
    int s = 0;
    for (int i = lo; i < hi; ++i) s += deg[i];
    part[tid] = s;
    __syncthreads();
    for (int off = 1; off < 1024; off <<= 1) {
        int v = (tid >= off) ? part[tid - off] : 0;
        __syncthreads();
        part[tid] += v;
        __syncthreads();
    }
    int run = (tid == 0) ? 0 : part[tid - 1];
    for (int i = lo; i < hi; ++i) {
        rowptr[i] = run;
        cursor[i] = run;
        run += deg[i];
    }
    if (tid == 1023) rowptr[n4] = run;
}

__global__ void edge_scatter_k(const int* __restrict__ ei, int E, int n, int qs,
                               int* __restrict__ cursor, int* __restrict__ srcs) {
    int i = blockIdx.x * blockDim.x + threadIdx.x;
    if (i >= E + n) return;
    int src, dst;
    if (i < E) { src = ei[i]; dst = ei[E + i]; }
    else       { src = i - E; dst = src; }
    int pos = atomicAdd(&cursor[dst * 4 + quad_of(src, qs)], 1);
    srcs[pos] = src;
}

// ---------------- bf16 split conversions ----------------
__global__ void split_bf16_k(const float* __restrict__ in, u16* __restrict__ hi,
                             u16* __restrict__ lo, int n4) {
    int i = blockIdx.x * 256 + threadIdx.x;
    if (i >= n4) return;
    float4 v = reinterpret_cast<const float4*>(in)[i];
    u16 hx = bf16rn(v.x), hy = bf16rn(v.y), hz = bf16rn(v.z), hw = bf16rn(v.w);
    ushort4 H = make_ushort4(hx, hy, hz, hw);
    ushort4 L = make_ushort4(bf16rn(v.x - bf16f(hx)), bf16rn(v.y - bf16f(hy)),
                             bf16rn(v.z - bf16f(hz)), bf16rn(v.w - bf16f(hw)));
    reinterpret_cast<ushort4*>(hi)[i] = H;
    reinterpret_cast<ushort4*>(lo)[i] = L;
}

// W[K][Nn] row-major -> transposed split Wt[Nn][K] (hi, lo)
__global__ void splitT_bf16_k(const float* __restrict__ W, u16* __restrict__ thi,
                              u16* __restrict__ tlo, int K, int Nn) {
    int idx = blockIdx.x * 256 + threadIdx.x;
    if (idx >= K * Nn) return;
    int k = idx / Nn, nn = idx - k * Nn;
    float v = W[idx];
    u16 h = bf16rn(v);
    u16 l = bf16rn(v - bf16f(h));
    thi[(size_t)nn * K + k] = h;
    tlo[(size_t)nn * K + k] = l;
}

// ---------------- split-bf16 MFMA GEMM, LDS-staged A, fused attn scores ----
// C emitted HEAD-MAJOR: C[((col>>6)*M + row)*64 + (col&63)].
// Epilogue also emits esrc/edst [M][Nn/64]: per-row dot with a_src/a_dst.
template <int NF>
__global__ __launch_bounds__(256) void gemm_lds_k(
        const u16* __restrict__ Ahi, const u16* __restrict__ Alo,
        const u16* __restrict__ Bthi, const u16* __restrict__ Btlo,
        float* __restrict__ C,
        const float* __restrict__ a_src, const float* __restrict__ a_dst,
        float* __restrict__ esrc, float* __restrict__ edst,
        int M, int Nn, int K) {
    __shared__ u16 Ah[2][4][64 * 8];   // [buf][kg][row*8]
    __shared__ u16 Al[2][4][64 * 8];
    const int mb = (M + 63) >> 6;
    const int mi = blockIdx.x % mb;
    const int ni = blockIdx.x / mb;
    const int m0 = mi * 64;
    const int n0 = ni * (NF * 64);
    const int tid = threadIdx.x;
    const int wv = tid >> 6;
    const int lane = tid & 63;
    const int rr = lane & 15;
    const int kg = lane >> 4;

    int srow = m0 + lane; if (srow > M - 1) srow = M - 1;
    const u16* sh = Ahi + (size_t)srow * K + wv * 8;
    const u16* sl = Alo + (size_t)srow * K + wv * 8;

    const u16* pbh[NF];
    const u16* pbl[NF];
#pragma unroll
    for (int nf = 0; nf < NF; ++nf) {
        int col = n0 + (wv * NF + nf) * 16 + rr;
        pbh[nf] = Bthi + (size_t)col * K + kg * 8;
        pbl[nf] = Btlo + (size_t)col * K + kg * 8;
    }

    f32x4 acc[4][NF];
#pragma unroll
    for (int mf = 0; mf < 4; ++mf)
#pragma unroll
        for (int nf = 0; nf < NF; ++nf) acc[mf][nf] = (f32x4){0.f, 0.f, 0.f, 0.f};

    bf16x8 bhc[NF], blc[NF], bhn[NF], bln[NF];
#pragma unroll
    for (int nf = 0; nf < NF; ++nf) {
        bhc[nf] = *reinterpret_cast<const bf16x8*>(pbh[nf]);
        blc[nf] = *reinterpret_cast<const bf16x8*>(pbl[nf]);
    }
    gload16(sh, &Ah[0][wv][0]);
    gload16(sl, &Al[0][wv][0]);
    __syncthreads();

    const int NT = K >> 5;
    for (int t = 0; t < NT; ++t) {
        const int cur = t & 1;
        if (t + 1 < NT) {
            const int kc = (t + 1) << 5;
#pragma unroll
            for (int nf = 0; nf < NF; ++nf) {
                bhn[nf] = *reinterpret_cast<const bf16x8*>(pbh[nf] + kc);
                bln[nf] = *reinterpret_cast<const bf16x8*>(pbl[nf] + kc);
            }
            gload16(sh + kc, &Ah[cur ^ 1][wv][0]);
            gload16(sl + kc, &Al[cur ^ 1][wv][0]);
        }
        bf16x8 ah[4], al[4];
#pragma unroll
        for (int mf = 0; mf < 4; ++mf) {
            ah[mf] = *reinterpret_cast<const bf16x8*>(&Ah[cur][kg][(mf * 16 + rr) * 8]);
            al[mf] = *reinterpret_cast<const bf16x8*>(&Al[cur][kg][(mf * 16 + rr) * 8]);
        }
#pragma unroll
        for (int mf = 0; mf < 4; ++mf)
#pragma unroll
            for (int nf = 0; nf < NF; ++nf) {
                acc[mf][nf] = __builtin_amdgcn_mfma_f32_16x16x32_bf16(ah[mf], bhc[nf], acc[mf][nf], 0, 0, 0);
                acc[mf][nf] = __builtin_amdgcn_mfma_f32_16x16x32_bf16(ah[mf], blc[nf], acc[mf][nf], 0, 0, 0);
                acc[mf][nf] = __builtin_amdgcn_mfma_f32_16x16x32_bf16(al[mf], bhc[nf], acc[mf][nf], 0, 0, 0);
            }
#pragma unroll
        for (int nf = 0; nf < NF; ++nf) { bhc[nf] = bhn[nf]; blc[nf] = bln[nf]; }
        __syncthreads();
    }

    // ---- C store (head-major) ----
#pragma unroll
    for (int mf = 0; mf < 4; ++mf)
#pragma unroll
        for (int nf = 0; nf < NF; ++nf) {
            int col = n0 + (wv * NF + nf) * 16 + rr;
            float* cb = C + ((size_t)(col >> 6) * M) * 64 + (col & 63);
#pragma unroll
            for (int rg = 0; rg < 4; ++rg) {
                int row = m0 + mf * 16 + kg * 4 + rg;
                if (row < M) cb[(size_t)row * 64] = acc[mf][nf][rg];
            }
        }

    // ---- fused attention scores: per-row dot with a_src / a_dst ----
    float asv[NF], adv[NF];
#pragma unroll
    for (int nf = 0; nf < NF; ++nf) {
        int col = n0 + (wv * NF + nf) * 16 + rr;
        asv[nf] = a_src[col];
        adv[nf] = a_dst[col];
    }
    float ps[4][4], pd[4][4];   // [mf][rg]
#pragma unroll
    for (int mf = 0; mf < 4; ++mf)
#pragma unroll
        for (int rg = 0; rg < 4; ++rg) {
            float s = 0.f, dvv = 0.f;
#pragma unroll
            for (int nf = 0; nf < NF; ++nf) {
                s = fmaf(acc[mf][nf][rg], asv[nf], s);
                dvv = fmaf(acc[mf][nf][rg], adv[nf], dvv);
            }
#pragma unroll
            for (int off = 1; off < 16; off <<= 1) {
                s += __shfl_xor(s, off);
                dvv += __shfl_xor(dvv, off);
            }
            ps[mf][rg] = s;
            pd[mf][rg] = dvv;
        }
    // cross-wave combine via LDS (reuse Ah; all reads of it completed)
    float* sm_src = (float*)&Ah[0][0][0];     // [4 waves][64 rows]
    float* sm_dst = sm_src + 256;
    if (rr == 0) {
#pragma unroll
        for (int mf = 0; mf < 4; ++mf)
#pragma unroll
            for (int rg = 0; rg < 4; ++rg) {
                int rl = mf * 16 + kg * 4 + rg;
                sm_src[wv * 64 + rl] = ps[mf][rg];
                sm_dst[wv * 64 + rl] = pd[mf][rg];
            }
    }
    __syncthreads();
    if (tid < 64) {
        int row = m0 + tid;
        if (row < M) {
            const int HTOT = Nn >> 6;
            constexpr int WPH = 4 / NF;        // waves per head
#pragma unroll
            for (int hl = 0; hl < NF; ++hl) {
                float es = 0.f, edv = 0.f;
#pragma unroll
                for (int w = 0; w < WPH; ++w) {
                    es += sm_src[(hl * WPH + w) * 64 + tid];
                    edv += sm_dst[(hl * WPH + w) * 64 + tid];
                }
                int hg = ni * NF + hl;
                esrc[(size_t)row * HTOT + hg] = es;
                edst[(size_t)row * HTOT + hg] = edv;
            }
        }
    }
}

// ---------------- GAT aggregation, head-split, LDS-staged {src,w} pairs ----
// hm head-major [4][n][64]. Wave per (dst,head); lane = (es=lane>>4, cq=lane&15).
// rowptr is (dst, src-quarter)-bucketed: row d spans [rp[4d], rp[4d+4]).
__global__ __launch_bounds__(256) void gat_aggregate_hm_k(
        const float* __restrict__ hm, const float* __restrict__ esrc,
        const float* __restrict__ edst, const int* __restrict__ rowptr,
        const int* __restrict__ srcs, const float* __restrict__ bias,
        u16* __restrict__ ghi, u16* __restrict__ glo, int n) {
    __shared__ int2 swb[4][64];
    int wv = threadIdx.x >> 6;
    int d = blockIdx.x * 4 + wv;
    int lane = threadIdx.x & 63;
    int hh = blockIdx.y;                        // head
    if (d >= n) return;
    const float* hbase = hm + (size_t)hh * n * 64;
    const int es = lane >> 4;                   // edge sub-slot 0..3
    const int cq = lane & 15;                   // channel quad
    int2* swv = swb[wv];
    float ed = edst[d * 4 + hh];
    int lo = rowptr[d * 4], hi = rowptr[d * 4 + 4];
    float4 acc = make_float4(0.f, 0.f, 0.f, 0.f);
    float den = 0.f;
    for (int base = lo; base < hi; base += 64) {
        int cnt = min(64, hi - base);
        int idx = base + lane;
        int s = srcs[(idx < hi) ? idx : lo];
        float e = esrc[s * 4 + hh] + ed;
        e = (e >= 0.f) ? e : 0.2f * e;          // leaky_relu(0.2)
        float w = (lane < cnt) ? __expf(e) : 0.f;
        float ws = w;
#pragma unroll
        for (int off = 1; off < 64; off <<= 1) ws += __shfl_xor(ws, off);
        den += ws;
        swv[lane] = make_int2(s, __float_as_int(w));   // same-wave LDS, no barrier
        auto ROW = [&](int2 sv) -> float4 {
            return *reinterpret_cast<const float4*>(&hbase[(size_t)sv.x * 64 + cq * 4]);
        };
        int2 s0 = swv[es], s1 = swv[4 + es], s2 = swv[8 + es], s3 = swv[12 + es];
        float4 p0 = ROW(s0), p1 = ROW(s1), p2 = ROW(s2), p3 = ROW(s3);
        for (int j = 0; j < cnt; j += 16) {
            int2 t0 = s0, t1 = s1, t2 = s2, t3 = s3;
            float4 q0 = p0, q1 = p1, q2 = p2, q3 = p3;
            s0 = swv[(j + 16 + es) & 63];
            s1 = swv[(j + 20 + es) & 63];
            s2 = swv[(j + 24 + es) & 63];
            s3 = swv[(j + 28 + es) & 63];
            p0 = ROW(s0); p1 = ROW(s1); p2 = ROW(s2); p3 = ROW(s3);
            float w0 = __int_as_float(t0.y), w1 = __int_as_float(t1.y);
            float w2 = __int_as_float(t2.y), w3 = __int_as_float(t3.y);
            acc.x = fmaf(w0, q0.x, acc.x); acc.y = fmaf(w0, q0.y, acc.y);
            acc.z = fmaf(w0, q0.z, acc.z); acc.w = fmaf(w0, q0.w, acc.w);
            acc.x = fmaf(w1, q1.x, acc.x); acc.y = fmaf(w1, q1.y, acc.y);
            acc.z = fmaf(w1, q1.z, acc.z); acc.w = fmaf(w1, q1.w, acc.w);
            acc.x = fmaf(w2, q2.x, acc.x); acc.y = fmaf(w2, q2.y, acc.y);
            acc.z = fmaf(w2, q2.z, acc.z); acc.w = fmaf(w2, q2.w, acc.w);
            acc.x = fmaf(w3, q3.x, acc.x); acc.y = fmaf(w3, q3.y, acc.y);
            acc.z = fmaf(w3, q3.z, acc.z); acc.w = fmaf(w3, q3.w, acc.w);
        }
    }
    // combine the 4 edge sub-slots (lanes differing in bits 4,5)
    acc.x += __shfl_xor(acc.x, 16); acc.x += __shfl_xor(acc.x, 32);
    acc.y += __shfl_xor(acc.y, 16); acc.y += __shfl_xor(acc.y, 32);
    acc.z += __shfl_xor(acc.z, 16); acc.z += __shfl_xor(acc.z, 32);
    acc.w += __shfl_xor(acc.w, 16); acc.w += __shfl_xor(acc.w, 32);
    if (es == 0) {
        int c0 = hh * 64 + cq * 4;
        float inv = 1.f / den;
        float4 bv = *reinterpret_cast<const float4*>(&bias[c0]);
        float4 o;
        o.x = acc.x * inv + bv.x;
        o.y = acc.y * inv + bv.y;
        o.z = acc.z * inv + bv.z;
        o.w = acc.w * inv + bv.w;
        o.x = (o.x > 0.f) ? o.x : expm1f(o.x);   // ELU
        o.y = (o.y > 0.f) ? o.y : expm1f(o.y);
        o.z = (o.z > 0.f) ? o.z : expm1f(o.z);
        o.w = (o.w > 0.f) ? o.w : expm1f(o.w);
        u16 hx = bf16rn(o.x), hy = bf16rn(o.y), hz = bf16rn(o.z), hw = bf16rn(o.w);
        ushort4 H = make_ushort4(hx, hy, hz, hw);
        ushort4 L = make_ushort4(bf16rn(o.x - bf16f(hx)), bf16rn(o.y - bf16f(hy)),
                                 bf16rn(o.z - bf16f(hz)), bf16rn(o.w - bf16f(hw)));
        *reinterpret_cast<ushort4*>(&ghi[(size_t)d * 256 + c0]) = H;
        *reinterpret_cast<ushort4*>(&glo[(size_t)d * 256 + c0]) = L;
    }
}

// ---------------- layer-3 aggregate (1 head) fused with node attn gate ------
__global__ __launch_bounds__(256) void gat_aggregate1_attn_k(
        const float* __restrict__ hin, const float* __restrict__ esrc,
        const float* __restrict__ edst, const int* __restrict__ rowptr,
        const int* __restrict__ srcs, const float* __restrict__ bias,
        const float* __restrict__ wp, const float* __restrict__ bp,
        float* __restrict__ gout, float* __restrict__ attn, int n) {
    __shared__ int2 swb[4][64];
    int wv = threadIdx.x >> 6;
    int d = blockIdx.x * 4 + wv;
    int lane = threadIdx.x & 63;
    if (d >= n) return;
    const int es = lane >> 4;
    const int cq = lane & 15;
    int2* swv = swb[wv];
    float ed = edst[d];
    int lo = rowptr[d * 4], hi = rowptr[d * 4 + 4];
    float4 acc = make_float4(0.f, 0.f, 0.f, 0.f);
    float den = 0.f;
    for (int base = lo; base < hi; base += 64) {
        int cnt = min(64, hi - base);
        int idx = base + lane;
        int s = srcs[(idx < hi) ? idx : lo];
        float e = esrc[s] + ed;
        e = (e >= 0.f) ? e : 0.2f * e;
        float w = (lane < cnt) ? __expf(e) : 0.f;
        float ws = w;
#pragma unroll
        for (int off = 1; off < 64; off <<= 1) ws += __shfl_xor(ws, off);
        den += ws;
        swv[lane] = make_int2(s, __float_as_int(w));
        auto ROW = [&](int2 sv) -> float4 {
            return *reinterpret_cast<const float4*>(&hin[(size_t)sv.x * 64 + cq * 4]);
        };
        int2 s0 = swv[es], s1 = swv[4 + es], s2 = swv[8 + es], s3 = swv[12 + es];
        float4 p0 = ROW(s0), p1 = ROW(s1), p2 = ROW(s2), p3 = ROW(s3);
        for (int j = 0; j < cnt; j += 16) {
            int2 t0 = s0, t1 = s1, t2 = s2, t3 = s3;
            float4 q0 = p0, q1 = p1, q2 = p2, q3 = p3;
            s0 = swv[(j + 16 + es) & 63];
            s1 = swv[(j + 20 + es) & 63];
            s2 = swv[(j + 24 + es) & 63];
            s3 = swv[(j + 28 + es) & 63];
            p0 = ROW(s0); p1 = ROW(s1); p2 = ROW(s2); p3 = ROW(s3);
            float w0 = __int_as_float(t0.y), w1 = __int_as_float(t1.y);
            float w2 = __int_as_float(t2.y), w3 = __int_as_float(t3.y);
            acc.x = fmaf(w0, q0.x, acc.x); acc.y = fmaf(w0, q0.y, acc.y);
            acc.z = fmaf(w0, q0.z, acc.z); acc.w = fmaf(w0, q0.w, acc.w);
            acc.x = fmaf(w1, q1.x, acc.x); acc.y = fmaf(w1, q1.y, acc.y);
            acc.z = fmaf(w1, q1.z, acc.z); acc.w = fmaf(w1, q1.w, acc.w);
            acc.x = fmaf(w2, q2.x, acc.x); acc.y = fmaf(w2, q2.y, acc.y);
            acc.z = fmaf(w2, q2.z, acc.z); acc.w = fmaf(w2, q2.w, acc.w);
            acc.x = fmaf(w3, q3.x, acc.x); acc.y = fmaf(w3, q3.y, acc.y);
            acc.z = fmaf(w3, q3.z, acc.z); acc.w = fmaf(w3, q3.w, acc.w);
        }
    }
    acc.x += __shfl_xor(acc.x, 16); acc.x += __shfl_xor(acc.x, 32);
    acc.y += __shfl_xor(acc.y, 16); acc.y += __shfl_xor(acc.y, 32);
    acc.z += __shfl_xor(acc.z, 16); acc.z += __shfl_xor(acc.z, 32);
    acc.w += __shfl_xor(acc.w, 16); acc.w += __shfl_xor(acc.w, 32);
    int c0 = cq * 4;
    float inv = 1.f / den;
    float4 bv = *reinterpret_cast<const float4*>(&bias[c0]);
    float4 o;
    o.x = acc.x * inv + bv.x;
    o.y = acc.y * inv + bv.y;
    o.z = acc.z * inv + bv.z;
    o.w = acc.w * inv + bv.w;
    o.x = (o.x > 0.f) ? o.x : expm1f(o.x);       // ELU
    o.y = (o.y > 0.f) ? o.y : expm1f(o.y);
    o.z = (o.z > 0.f) ? o.z : expm1f(o.z);
    o.w = (o.w > 0.f) ? o.w : expm1f(o.w);
    if (es == 0)
        *reinterpret_cast<float4*>(&gout[(size_t)d * 64 + c0]) = o;
    // node attention gate: full 64-ch dot (cq lanes each hold 4 channels)
    float4 wv4 = *reinterpret_cast<const float4*>(&wp[c0]);
    float v = o.x * wv4.x + o.y * wv4.y + o.z * wv4.z + o.w * wv4.w;
#pragma unroll
    for (int off = 1; off < 16; off <<= 1) v += __shfl_xor(v, off);
    if (lane == 0) attn[d] = 1.f / (1.f + __expf(-(v + bp[0])));
}

// ---------------- parallel segmented pooling (batch is sorted) --------------
__global__ void pool_partial_k(const float* __restrict__ g3, const float* __restrict__ attn,
                               const int* __restrict__ batch, int n, float* __restrict__ sums) {
    int wid = blockIdx.x * (blockDim.x >> 6) + (threadIdx.x >> 6);
    int lane = threadIdx.x & 63;
    int nwaves = gridDim.x * (blockDim.x >> 6);
    int per = (n + nwaves - 1) / nwaves;
    int i0 = wid * per;
    int i1 = i0 + per;
    if (i1 > n) i1 = n;
    if (i0 >= i1) return;
    int cur = batch[i0];
    float acc = 0.f;
    for (int i = i0; i < i1; ++i) {
        int b = batch[i];
        if (b != cur) {
            atomicAdd(&sums[cur * 64 + lane], acc);
            acc = 0.f;
            cur = b;
        }
        acc += g3[(size_t)i * 64 + lane] * attn[i];
    }
    atomicAdd(&sums[cur * 64 + lane], acc);
}

// ---------------- final regressor: one block, wave per graph ----------------
__global__ void regress_k(const float* __restrict__ sums, const int* __restrict__ batch, int n,
                          const float* __restrict__ wr, const float* __restrict__ br,
                          float* __restrict__ out, int B) {
    int b = threadIdx.x >> 6;
    int lane = threadIdx.x & 63;
    if (b >= B) return;
    int lo = 0, hi = n;
    while (lo < hi) { int mid = (lo + hi) >> 1; if (batch[mid] < b) lo = mid + 1; else hi = mid; }
    int seg_lo = lo;
    lo = 0; hi = n;
    while (lo < hi) { int mid = (lo + hi) >> 1; if (batch[mid] < b + 1) lo = mid + 1; else hi = mid; }
    float cnt = (float)(lo - seg_lo);
    if (cnt < 1.f) cnt = 1.f;
    float v = (sums[b * 64 + lane] / cnt) * wr[lane];
#pragma unroll
    for (int off = 32; off; off >>= 1) v += __shfl_xor(v, off);
    if (lane == 0) out[b] = v + br[0];
}

// ---------------------------------------------------------------------------
extern "C" void kernel_launch(void* const* d_in, const int* in_sizes, int n_in,
                              void* d_out, int out_size, void* d_ws, size_t ws_size,
                              hipStream_t stream) {
    const float* x   = (const float*)d_in[0];
    const int*   ei  = (const int*)d_in[1];
    const int*   bat = (const int*)d_in[2];
    const float* W1  = (const float*)d_in[3];
    const float* as1 = (const float*)d_in[4];
    const float* ad1 = (const float*)d_in[5];
    const float* b1  = (const float*)d_in[6];
    const float* W2  = (const float*)d_in[7];
    const float* as2 = (const float*)d_in[8];
    const float* ad2 = (const float*)d_in[9];
    const float* b2  = (const float*)d_in[10];
    const float* W3  = (const float*)d_in[11];
    const float* as3 = (const float*)d_in[12];
    const float* ad3 = (const float*)d_in[13];
    const float* b3  = (const float*)d_in[14];
    const float* wp  = (const float*)d_in[15];
    const float* bp  = (const float*)d_in[16];
    const float* wr  = (const float*)d_in[17];
    const float* br  = (const float*)d_in[18];
    float* out = (float*)d_out;

    const int N    = in_sizes[2];          // 20000
    const int E    = in_sizes[1] / 2;      // 320000
    const int DIN  = in_sizes[0] / N;      // 128
    const int Etot = E + N;
    const int Bc   = out_size;             // 16
    const int qs   = (N + 3) / 4;          // src-quarter size

    char* ws = (char*)d_ws;
    size_t off = 0;
    auto alloc = [&](size_t bytes) {
        void* p = ws + off;
        off = (off + bytes + 255) & ~(size_t)255;
        return p;
    };
    int*   deg    = (int*)alloc((size_t)N * 4 * 4);
    int*   rowptr = (int*)alloc(((size_t)N * 4 + 1) * 4);
    int*   cursor = (int*)alloc((size_t)N * 4 * 4);
    int*   srcs   = (int*)alloc((size_t)Etot * 4);
    float* bufA   = (float*)alloc((size_t)N * 256 * 4);     // GEMM out h (head-major)
    u16*   Ahi    = (u16*)alloc((size_t)N * 256 * 2);       // x/g split hi
    u16*   Alo    = (u16*)alloc((size_t)N * 256 * 2);       // x/g split lo
    float* h3     = (float*)alloc((size_t)N * 64 * 4);
    float* g3     = (float*)alloc((size_t)N * 64 * 4);
    float* esrc   = (float*)alloc((size_t)N * 4 * 4);
    float* edst   = (float*)alloc((size_t)N * 4 * 4);
    float* attn   = (float*)alloc((size_t)N * 4);
    float* sums   = (float*)alloc((size_t)Bc * 64 * 4);
    u16*   w1hi   = (u16*)alloc((size_t)256 * DIN * 2);
    u16*   w1lo   = (u16*)alloc((size_t)256 * DIN * 2);
    u16*   w2hi   = (u16*)alloc((size_t)256 * 256 * 2);
    u16*   w2lo   = (u16*)alloc((size_t)256 * 256 * 2);
    u16*   w3hi   = (u16*)alloc((size_t)64 * 256 * 2);
    u16*   w3lo   = (u16*)alloc((size_t)64 * 256 * 2);
    (void)ws_size;

    // CSR build, (dst, src-quarter)-bucketed (shared by all layers)
    hipMemsetAsync(deg, 0, (size_t)N * 4 * 4, stream);
    int eb = (Etot + 255) / 256;
    edge_hist_k<<<eb, 256, 0, stream>>>(ei, E, N, qs, deg);
    scan_excl_k<<<1, 1024, 0, stream>>>(deg, rowptr, cursor, N * 4);
    edge_scatter_k<<<eb, 256, 0, stream>>>(ei, E, N, qs, cursor, srcs);

    // weight splits (transposed) + x split
    splitT_bf16_k<<<(DIN * 256 + 255) / 256, 256, 0, stream>>>(W1, w1hi, w1lo, DIN, 256);
    splitT_bf16_k<<<(256 * 256 + 255) / 256, 256, 0, stream>>>(W2, w2hi, w2lo, 256, 256);
    splitT_bf16_k<<<(256 * 64 + 255) / 256, 256, 0, stream>>>(W3, w3hi, w3lo, 256, 64);
    split_bf16_k<<<(N * DIN / 4 + 255) / 256, 256, 0, stream>>>(x, Ahi, Alo, N * DIN / 4);

    const int mb = (N + 63) / 64;          // 313
    int nb4 = (N + 3) / 4;
    dim3 agg_grid(nb4, 4);

    // Layer 1: DIN -> (4,64) concat      (BN=128 -> 2 n-tiles)
    gemm_lds_k<2><<<mb * 2, 256, 0, stream>>>(Ahi, Alo, w1hi, w1lo, bufA, as1, ad1, esrc, edst, N, 256, DIN);
    gat_aggregate_hm_k<<<agg_grid, 256, 0, stream>>>(bufA, esrc, edst, rowptr, srcs, b1, Ahi, Alo, N);

    // Layer 2: 256 -> (4,64) concat
    gemm_lds_k<2><<<mb * 2, 256, 0, stream>>>(Ahi, Alo, w2hi, w2lo, bufA, as2, ad2, esrc, edst, N, 256, 256);
    gat_aggregate_hm_k<<<agg_grid, 256, 0, stream>>>(bufA, esrc, edst, rowptr, srcs, b2, Ahi, Alo, N);

    // Layer 3: 256 -> (1,64) mean + fused node-attention gate   (BN=64)
    gemm_lds_k<1><<<mb, 256, 0, stream>>>(Ahi, Alo, w3hi, w3lo, h3, as3, ad3, esrc, edst, N, 64, 256);
    gat_aggregate1_attn_k<<<nb4, 256, 0, stream>>>(h3, esrc, edst, rowptr, srcs, b3, wp, bp, g3, attn, N);

    // Attention pool + regressor (parallel)
    hipMemsetAsync(sums, 0, (size_t)Bc * 64 * 4, stream);
    pool_partial_k<<<256, 256, 0, stream>>>(g3, attn, bat, N, sums);
    regress_k<<<1, 1024, 0, stream>>>(sums, bat, N, wr, br, out, Bc);
}

// Round 13
// 251.002 us; speedup vs baseline: 1.6409x; 1.6409x over previous
//
#include <hip/hip_runtime.h>

// ---------------------------------------------------------------------------
// GAT (3 layers) + attention pooling + regressor.
// GEMMs: split-bf16 MFMA (a_hi+a_lo, 3 products, f32 accum), A staged in LDS
// via global_load_lds; attn scores fused into GEMM epilogue; h stored
// HEAD-MAJOR [H][N][64] (5.1MB/head gather set).
// CSR by dst; rowptr built with a 3-pass hierarchical parallel scan.
// Aggregates: LDS-staged {src,w} pairs, 4 edges/instruction, float4 rows.
// N=20000 nodes, E=320000 edges (+N self loops), H=4 heads, C=64, B=16 graphs.
// ---------------------------------------------------------------------------

typedef unsigned short u16;
typedef __attribute__((ext_vector_type(8))) short bf16x8;
typedef __attribute__((ext_vector_type(4))) float f32x4;

__device__ __forceinline__ u16 bf16rn(float x) {
    unsigned u = __float_as_uint(x);
    u += 0x7FFFu + ((u >> 16) & 1u);
    return (u16)(u >> 16);
}
__device__ __forceinline__ float bf16f(u16 h) {
    return __uint_as_float(((unsigned)h) << 16);
}

__device__ __forceinline__ void gload16(const u16* g, u16* l) {
    __builtin_amdgcn_global_load_lds(
        (const __attribute__((address_space(1))) unsigned int*)g,
        (__attribute__((address_space(3))) unsigned int*)l, 16, 0, 0);
}

// ---------------- CSR-by-destination build ----------------
__global__ void edge_hist_k(const int* __restrict__ ei, int E, int n, int* __restrict__ deg) {
    int i = blockIdx.x * blockDim.x + threadIdx.x;
    if (i >= E + n) return;
    int dst = (i < E) ? ei[E + i] : (i - E);   // self-loop for i >= E
    atomicAdd(&deg[dst], 1);
}

// 3-pass hierarchical exclusive scan (replaces the 177us single-block scan).
__global__ void scan_p1_k(const int* __restrict__ deg, int* __restrict__ bsum, int n) {
    __shared__ int red[256];
    int tid = threadIdx.x;
    int i = blockIdx.x * 256 + tid;
    int v = (i < n) ? deg[i] : 0;
    red[tid] = v;
    __syncthreads();
    for (int off = 128; off; off >>= 1) {
        if (tid < off) red[tid] += red[tid + off];
        __syncthreads();
    }
    if (tid == 0) bsum[blockIdx.x] = red[0];
}

__global__ __launch_bounds__(1024) void scan_p2_k(int* __restrict__ bsum, int nb) {
    __shared__ int part[1024];
    int tid = threadIdx.x;
    int v = (tid < nb) ? bsum[tid] : 0;
    part[tid] = v;
    __syncthreads();
    for (int off = 1; off < 1024; off <<= 1) {
        int t = (tid >= off) ? part[tid - off] : 0;
        __syncthreads();
        part[tid] += t;
        __syncthreads();
    }
    if (tid < nb) bsum[tid] = part[tid] - v;      // exclusive
}

__global__ void scan_p3_k(const int* __restrict__ deg, const int* __restrict__ bsum,
                          int* __restrict__ rowptr, int* __restrict__ cursor, int n) {
    __shared__ int part[256];
    int tid = threadIdx.x;
    int i = blockIdx.x * 256 + tid;
    int v = (i < n) ? deg[i] : 0;
    part[tid] = v;
    __syncthreads();
    for (int off = 1; off < 256; off <<= 1) {
        int t = (tid >= off) ? part[tid - off] : 0;
        __syncthreads();
        part[tid] += t;
        __syncthreads();
    }
    int excl = part[tid] - v + bsum[blockIdx.x];
    if (i < n) { rowptr[i] = excl; cursor[i] = excl; }
    if (i == n - 1) rowptr[n] = excl + v;
}

__global__ void edge_scatter_k(const int* __restrict__ ei, int E, int n,
                               int* __restrict__ cursor, int* __restrict__ srcs) {
    int i = blockIdx.x * blockDim.x + threadIdx.x;
    if (i >= E + n) return;
    int src, dst;
    if (i < E) { src = ei[i]; dst = ei[E + i]; }
    else       { src = i - E; dst = src; }
    int pos = atomicAdd(&cursor[dst], 1);
    srcs[pos] = src;
}

// ---------------- bf16 split conversions ----------------
__global__ void split_bf16_k(const float* __restrict__ in, u16* __restrict__ hi,
                             u16* __restrict__ lo, int n4) {
    int i = blockIdx.x * 256 + threadIdx.x;
    if (i >= n4) return;
    float4 v = reinterpret_cast<const float4*>(in)[i];
    u16 hx = bf16rn(v.x), hy = bf16rn(v.y), hz = bf16rn(v.z), hw = bf16rn(v.w);
    ushort4 H = make_ushort4(hx, hy, hz, hw);
    ushort4 L = make_ushort4(bf16rn(v.x - bf16f(hx)), bf16rn(v.y - bf16f(hy)),
                             bf16rn(v.z - bf16f(hz)), bf16rn(v.w - bf16f(hw)));
    reinterpret_cast<ushort4*>(hi)[i] = H;
    reinterpret_cast<ushort4*>(lo)[i] = L;
}

// W[K][Nn] row-major -> transposed split Wt[Nn][K] (hi, lo)
__global__ void splitT_bf16_k(const float* __restrict__ W, u16* __restrict__ thi,
                              u16* __restrict__ tlo, int K, int Nn) {
    int idx = blockIdx.x * 256 + threadIdx.x;
    if (idx >= K * Nn) return;
    int k = idx / Nn, nn = idx - k * Nn;
    float v = W[idx];
    u16 h = bf16rn(v);
    u16 l = bf16rn(v - bf16f(h));
    thi[(size_t)nn * K + k] = h;
    tlo[(size_t)nn * K + k] = l;
}

// ---------------- split-bf16 MFMA GEMM, LDS-staged A, fused attn scores ----
// C emitted HEAD-MAJOR: C[((col>>6)*M + row)*64 + (col&63)].
// Epilogue also emits esrc/edst [M][Nn/64]: per-row dot with a_src/a_dst.
template <int NF>
__global__ __launch_bounds__(256) void gemm_lds_k(
        const u16* __restrict__ Ahi, const u16* __restrict__ Alo,
        const u16* __restrict__ Bthi, const u16* __restrict__ Btlo,
        float* __restrict__ C,
        const float* __restrict__ a_src, const float* __restrict__ a_dst,
        float* __restrict__ esrc, float* __restrict__ edst,
        int M, int Nn, int K) {
    __shared__ u16 Ah[2][4][64 * 8];   // [buf][kg][row*8]
    __shared__ u16 Al[2][4][64 * 8];
    const int mb = (M + 63) >> 6;
    const int mi = blockIdx.x % mb;
    const int ni = blockIdx.x / mb;
    const int m0 = mi * 64;
    const int n0 = ni * (NF * 64);
    const int tid = threadIdx.x;
    const int wv = tid >> 6;
    const int lane = tid & 63;
    const int rr = lane & 15;
    const int kg = lane >> 4;

    int srow = m0 + lane; if (srow > M - 1) srow = M - 1;
    const u16* sh = Ahi + (size_t)srow * K + wv * 8;
    const u16* sl = Alo + (size_t)srow * K + wv * 8;

    const u16* pbh[NF];
    const u16* pbl[NF];
#pragma unroll
    for (int nf = 0; nf < NF; ++nf) {
        int col = n0 + (wv * NF + nf) * 16 + rr;
        pbh[nf] = Bthi + (size_t)col * K + kg * 8;
        pbl[nf] = Btlo + (size_t)col * K + kg * 8;
    }

    f32x4 acc[4][NF];
#pragma unroll
    for (int mf = 0; mf < 4; ++mf)
#pragma unroll
        for (int nf = 0; nf < NF; ++nf) acc[mf][nf] = (f32x4){0.f, 0.f, 0.f, 0.f};

    bf16x8 bhc[NF], blc[NF], bhn[NF], bln[NF];
#pragma unroll
    for (int nf = 0; nf < NF; ++nf) {
        bhc[nf] = *reinterpret_cast<const bf16x8*>(pbh[nf]);
        blc[nf] = *reinterpret_cast<const bf16x8*>(pbl[nf]);
    }
    gload16(sh, &Ah[0][wv][0]);
    gload16(sl, &Al[0][wv][0]);
    __syncthreads();

    const int NT = K >> 5;
    for (int t = 0; t < NT; ++t) {
        const int cur = t & 1;
        if (t + 1 < NT) {
            const int kc = (t + 1) << 5;
#pragma unroll
            for (int nf = 0; nf < NF; ++nf) {
                bhn[nf] = *reinterpret_cast<const bf16x8*>(pbh[nf] + kc);
                bln[nf] = *reinterpret_cast<const bf16x8*>(pbl[nf] + kc);
            }
            gload16(sh + kc, &Ah[cur ^ 1][wv][0]);
            gload16(sl + kc, &Al[cur ^ 1][wv][0]);
        }
        bf16x8 ah[4], al[4];
#pragma unroll
        for (int mf = 0; mf < 4; ++mf) {
            ah[mf] = *reinterpret_cast<const bf16x8*>(&Ah[cur][kg][(mf * 16 + rr) * 8]);
            al[mf] = *reinterpret_cast<const bf16x8*>(&Al[cur][kg][(mf * 16 + rr) * 8]);
        }
#pragma unroll
        for (int mf = 0; mf < 4; ++mf)
#pragma unroll
            for (int nf = 0; nf < NF; ++nf) {
                acc[mf][nf] = __builtin_amdgcn_mfma_f32_16x16x32_bf16(ah[mf], bhc[nf], acc[mf][nf], 0, 0, 0);
                acc[mf][nf] = __builtin_amdgcn_mfma_f32_16x16x32_bf16(ah[mf], blc[nf], acc[mf][nf], 0, 0, 0);
                acc[mf][nf] = __builtin_amdgcn_mfma_f32_16x16x32_bf16(al[mf], bhc[nf], acc[mf][nf], 0, 0, 0);
            }
#pragma unroll
        for (int nf = 0; nf < NF; ++nf) { bhc[nf] = bhn[nf]; blc[nf] = bln[nf]; }
        __syncthreads();
    }

    // ---- C store (head-major) ----
#pragma unroll
    for (int mf = 0; mf < 4; ++mf)
#pragma unroll
        for (int nf = 0; nf < NF; ++nf) {
            int col = n0 + (wv * NF + nf) * 16 + rr;
            float* cb = C + ((size_t)(col >> 6) * M) * 64 + (col & 63);
#pragma unroll
            for (int rg = 0; rg < 4; ++rg) {
                int row = m0 + mf * 16 + kg * 4 + rg;
                if (row < M) cb[(size_t)row * 64] = acc[mf][nf][rg];
            }
        }

    // ---- fused attention scores: per-row dot with a_src / a_dst ----
    float asv[NF], adv[NF];
#pragma unroll
    for (int nf = 0; nf < NF; ++nf) {
        int col = n0 + (wv * NF + nf) * 16 + rr;
        asv[nf] = a_src[col];
        adv[nf] = a_dst[col];
    }
    float ps[4][4], pd[4][4];   // [mf][rg]
#pragma unroll
    for (int mf = 0; mf < 4; ++mf)
#pragma unroll
        for (int rg = 0; rg < 4; ++rg) {
            float s = 0.f, dvv = 0.f;
#pragma unroll
            for (int nf = 0; nf < NF; ++nf) {
                s = fmaf(acc[mf][nf][rg], asv[nf], s);
                dvv = fmaf(acc[mf][nf][rg], adv[nf], dvv);
            }
#pragma unroll
            for (int off = 1; off < 16; off <<= 1) {
                s += __shfl_xor(s, off);
                dvv += __shfl_xor(dvv, off);
            }
            ps[mf][rg] = s;
            pd[mf][rg] = dvv;
        }
    // cross-wave combine via LDS (reuse Ah; all reads of it completed)
    float* sm_src = (float*)&Ah[0][0][0];     // [4 waves][64 rows]
    float* sm_dst = sm_src + 256;
    if (rr == 0) {
#pragma unroll
        for (int mf = 0; mf < 4; ++mf)
#pragma unroll
            for (int rg = 0; rg < 4; ++rg) {
                int rl = mf * 16 + kg * 4 + rg;
                sm_src[wv * 64 + rl] = ps[mf][rg];
                sm_dst[wv * 64 + rl] = pd[mf][rg];
            }
    }
    __syncthreads();
    if (tid < 64) {
        int row = m0 + tid;
        if (row < M) {
            const int HTOT = Nn >> 6;
            constexpr int WPH = 4 / NF;        // waves per head
#pragma unroll
            for (int hl = 0; hl < NF; ++hl) {
                float es = 0.f, edv = 0.f;
#pragma unroll
                for (int w = 0; w < WPH; ++w) {
                    es += sm_src[(hl * WPH + w) * 64 + tid];
                    edv += sm_dst[(hl * WPH + w) * 64 + tid];
                }
                int hg = ni * NF + hl;
                esrc[(size_t)row * HTOT + hg] = es;
                edst[(size_t)row * HTOT + hg] = edv;
            }
        }
    }
}

// ---------------- GAT aggregation, head-split, LDS-staged {src,w} pairs ----
// hm head-major [4][n][64]. Wave per (dst,head); lane = (es=lane>>4, cq=lane&15).
__global__ __launch_bounds__(256) void gat_aggregate_hm_k(
        const float* __restrict__ hm, const float* __restrict__ esrc,
        const float* __restrict__ edst, const int* __restrict__ rowptr,
        const int* __restrict__ srcs, const float* __restrict__ bias,
        u16* __restrict__ ghi, u16* __restrict__ glo, int n) {
    __shared__ int2 swb[4][64];
    int wv = threadIdx.x >> 6;
    int d = blockIdx.x * 4 + wv;
    int lane = threadIdx.x & 63;
    int hh = blockIdx.y;                        // head
    if (d >= n) return;
    const float* hbase = hm + (size_t)hh * n * 64;
    const int es = lane >> 4;                   // edge sub-slot 0..3
    const int cq = lane & 15;                   // channel quad
    int2* swv = swb[wv];
    float ed = edst[d * 4 + hh];
    int lo = rowptr[d], hi = rowptr[d + 1];
    float4 acc = make_float4(0.f, 0.f, 0.f, 0.f);
    float den = 0.f;
    for (int base = lo; base < hi; base += 64) {
        int cnt = min(64, hi - base);
        int idx = base + lane;
        int s = srcs[(idx < hi) ? idx : lo];
        float e = esrc[s * 4 + hh] + ed;
        e = (e >= 0.f) ? e : 0.2f * e;          // leaky_relu(0.2)
        float w = (lane < cnt) ? __expf(e) : 0.f;
        float ws = w;
#pragma unroll
        for (int off = 1; off < 64; off <<= 1) ws += __shfl_xor(ws, off);
        den += ws;
        swv[lane] = make_int2(s, __float_as_int(w));   // same-wave LDS, no barrier
        auto ROW = [&](int2 sv) -> float4 {
            return *reinterpret_cast<const float4*>(&hbase[(size_t)sv.x * 64 + cq * 4]);
        };
        int2 s0 = swv[es], s1 = swv[4 + es], s2 = swv[8 + es], s3 = swv[12 + es];
        float4 p0 = ROW(s0), p1 = ROW(s1), p2 = ROW(s2), p3 = ROW(s3);
        for (int j = 0; j < cnt; j += 16) {
            int2 t0 = s0, t1 = s1, t2 = s2, t3 = s3;
            float4 q0 = p0, q1 = p1, q2 = p2, q3 = p3;
            s0 = swv[(j + 16 + es) & 63];
            s1 = swv[(j + 20 + es) & 63];
            s2 = swv[(j + 24 + es) & 63];
            s3 = swv[(j + 28 + es) & 63];
            p0 = ROW(s0); p1 = ROW(s1); p2 = ROW(s2); p3 = ROW(s3);
            float w0 = __int_as_float(t0.y), w1 = __int_as_float(t1.y);
            float w2 = __int_as_float(t2.y), w3 = __int_as_float(t3.y);
            acc.x = fmaf(w0, q0.x, acc.x); acc.y = fmaf(w0, q0.y, acc.y);
            acc.z = fmaf(w0, q0.z, acc.z); acc.w = fmaf(w0, q0.w, acc.w);
            acc.x = fmaf(w1, q1.x, acc.x); acc.y = fmaf(w1, q1.y, acc.y);
            acc.z = fmaf(w1, q1.z, acc.z); acc.w = fmaf(w1, q1.w, acc.w);
            acc.x = fmaf(w2, q2.x, acc.x); acc.y = fmaf(w2, q2.y, acc.y);
            acc.z = fmaf(w2, q2.z, acc.z); acc.w = fmaf(w2, q2.w, acc.w);
            acc.x = fmaf(w3, q3.x, acc.x); acc.y = fmaf(w3, q3.y, acc.y);
            acc.z = fmaf(w3, q3.z, acc.z); acc.w = fmaf(w3, q3.w, acc.w);
        }
    }
    // combine the 4 edge sub-slots (lanes differing in bits 4,5)
    acc.x += __shfl_xor(acc.x, 16); acc.x += __shfl_xor(acc.x, 32);
    acc.y += __shfl_xor(acc.y, 16); acc.y += __shfl_xor(acc.y, 32);
    acc.z += __shfl_xor(acc.z, 16); acc.z += __shfl_xor(acc.z, 32);
    acc.w += __shfl_xor(acc.w, 16); acc.w += __shfl_xor(acc.w, 32);
    if (es == 0) {
        int c0 = hh * 64 + cq * 4;
        float inv = 1.f / den;
        float4 bv = *reinterpret_cast<const float4*>(&bias[c0]);
        float4 o;
        o.x = acc.x * inv + bv.x;
        o.y = acc.y * inv + bv.y;
        o.z = acc.z * inv + bv.z;
        o.w = acc.w * inv + bv.w;
        o.x = (o.x > 0.f) ? o.x : expm1f(o.x);   // ELU
        o.y = (o.y > 0.f) ? o.y : expm1f(o.y);
        o.z = (o.z > 0.f) ? o.z : expm1f(o.z);
        o.w = (o.w > 0.f) ? o.w : expm1f(o.w);
        u16 hx = bf16rn(o.x), hy = bf16rn(o.y), hz = bf16rn(o.z), hw = bf16rn(o.w);
        ushort4 H = make_ushort4(hx, hy, hz, hw);
        ushort4 L = make_ushort4(bf16rn(o.x - bf16f(hx)), bf16rn(o.y - bf16f(hy)),
                                 bf16rn(o.z - bf16f(hz)), bf16rn(o.w - bf16f(hw)));
        *reinterpret_cast<ushort4*>(&ghi[(size_t)d * 256 + c0]) = H;
        *reinterpret_cast<ushort4*>(&glo[(size_t)d * 256 + c0]) = L;
    }
}

// ---------------- layer-3 aggregate (1 head) fused with node attn gate ------
__global__ __launch_bounds__(256) void gat_aggregate1_attn_k(
        const float* __restrict__ hin, const float* __restrict__ esrc,
        const float* __restrict__ edst, const int* __restrict__ rowptr,
        const int* __restrict__ srcs, const float* __restrict__ bias,
        const float* __restrict__ wp, const float* __restrict__ bp,
        float* __restrict__ gout, float* __restrict__ attn, int n) {
    __shared__ int2 swb[4][64];
    int wv = threadIdx.x >> 6;
    int d = blockIdx.x * 4 + wv;
    int lane = threadIdx.x & 63;
    if (d >= n) return;
    const int es = lane >> 4;
    const int cq = lane & 15;
    int2* swv = swb[wv];
    float ed = edst[d];
    int lo = rowptr[d], hi = rowptr[d + 1];
    float4 acc = make_float4(0.f, 0.f, 0.f, 0.f);
    float den = 0.f;
    for (int base = lo; base < hi; base += 64) {
        int cnt = min(64, hi - base);
        int idx = base + lane;
        int s = srcs[(idx < hi) ? idx : lo];
        float e = esrc[s] + ed;
        e = (e >= 0.f) ? e : 0.2f * e;
        float w = (lane < cnt) ? __expf(e) : 0.f;
        float ws = w;
#pragma unroll
        for (int off = 1; off < 64; off <<= 1) ws += __shfl_xor(ws, off);
        den += ws;
        swv[lane] = make_int2(s, __float_as_int(w));
        auto ROW = [&](int2 sv) -> float4 {
            return *reinterpret_cast<const float4*>(&hin[(size_t)sv.x * 64 + cq * 4]);
        };
        int2 s0 = swv[es], s1 = swv[4 + es], s2 = swv[8 + es], s3 = swv[12 + es];
        float4 p0 = ROW(s0), p1 = ROW(s1), p2 = ROW(s2), p3 = ROW(s3);
        for (int j = 0; j < cnt; j += 16) {
            int2 t0 = s0, t1 = s1, t2 = s2, t3 = s3;
            float4 q0 = p0, q1 = p1, q2 = p2, q3 = p3;
            s0 = swv[(j + 16 + es) & 63];
            s1 = swv[(j + 20 + es) & 63];
            s2 = swv[(j + 24 + es) & 63];
            s3 = swv[(j + 28 + es) & 63];
            p0 = ROW(s0); p1 = ROW(s1); p2 = ROW(s2); p3 = ROW(s3);
            float w0 = __int_as_float(t0.y), w1 = __int_as_float(t1.y);
            float w2 = __int_as_float(t2.y), w3 = __int_as_float(t3.y);
            acc.x = fmaf(w0, q0.x, acc.x); acc.y = fmaf(w0, q0.y, acc.y);
            acc.z = fmaf(w0, q0.z, acc.z); acc.w = fmaf(w0, q0.w, acc.w);
            acc.x = fmaf(w1, q1.x, acc.x); acc.y = fmaf(w1, q1.y, acc.y);
            acc.z = fmaf(w1, q1.z, acc.z); acc.w = fmaf(w1, q1.w, acc.w);
            acc.x = fmaf(w2, q2.x, acc.x); acc.y = fmaf(w2, q2.y, acc.y);
            acc.z = fmaf(w2, q2.z, acc.z); acc.w = fmaf(w2, q2.w, acc.w);
            acc.x = fmaf(w3, q3.x, acc.x); acc.y = fmaf(w3, q3.y, acc.y);
            acc.z = fmaf(w3, q3.z, acc.z); acc.w = fmaf(w3, q3.w, acc.w);
        }
    }
    acc.x += __shfl_xor(acc.x, 16); acc.x += __shfl_xor(acc.x, 32);
    acc.y += __shfl_xor(acc.y, 16); acc.y += __shfl_xor(acc.y, 32);
    acc.z += __shfl_xor(acc.z, 16); acc.z += __shfl_xor(acc.z, 32);
    acc.w += __shfl_xor(acc.w, 16); acc.w += __shfl_xor(acc.w, 32);
    int c0 = cq * 4;
    float inv = 1.f / den;
    float4 bv = *reinterpret_cast<const float4*>(&bias[c0]);
    float4 o;
    o.x = acc.x * inv + bv.x;
    o.y = acc.y * inv + bv.y;
    o.z = acc.z * inv + bv.z;
    o.w = acc.w * inv + bv.w;
    o.x = (o.x > 0.f) ? o.x : expm1f(o.x);       // ELU
    o.y = (o.y > 0.f) ? o.y : expm1f(o.y);
    o.z = (o.z > 0.f) ? o.z : expm1f(o.z);
    o.w = (o.w > 0.f) ? o.w : expm1f(o.w);
    if (es == 0)
        *reinterpret_cast<float4*>(&gout[(size_t)d * 64 + c0]) = o;
    // node attention gate: full 64-ch dot (cq lanes each hold 4 channels)
    float4 wv4 = *reinterpret_cast<const float4*>(&wp[c0]);
    float v = o.x * wv4.x + o.y * wv4.y + o.z * wv4.z + o.w * wv4.w;
#pragma unroll
    for (int off = 1; off < 16; off <<= 1) v += __shfl_xor(v, off);
    if (lane == 0) attn[d] = 1.f / (1.f + __expf(-(v + bp[0])));
}

// ---------------- parallel segmented pooling (batch is sorted) --------------
__global__ void pool_partial_k(const float* __restrict__ g3, const float* __restrict__ attn,
                               const int* __restrict__ batch, int n, float* __restrict__ sums) {
    int wid = blockIdx.x * (blockDim.x >> 6) + (threadIdx.x >> 6);
    int lane = threadIdx.x & 63;
    int nwaves = gridDim.x * (blockDim.x >> 6);
    int per = (n + nwaves - 1) / nwaves;
    int i0 = wid * per;
    int i1 = i0 + per;
    if (i1 > n) i1 = n;
    if (i0 >= i1) return;
    int cur = batch[i0];
    float acc = 0.f;
    for (int i = i0; i < i1; ++i) {
        int b = batch[i];
        if (b != cur) {
            atomicAdd(&sums[cur * 64 + lane], acc);
            acc = 0.f;
            cur = b;
        }
        acc += g3[(size_t)i * 64 + lane] * attn[i];
    }
    atomicAdd(&sums[cur * 64 + lane], acc);
}

// ---------------- final regressor: one block, wave per graph ----------------
__global__ void regress_k(const float* __restrict__ sums, const int* __restrict__ batch, int n,
                          const float* __restrict__ wr, const float* __restrict__ br,
                          float* __restrict__ out, int B) {
    int b = threadIdx.x >> 6;
    int lane = threadIdx.x & 63;
    if (b >= B) return;
    int lo = 0, hi = n;
    while (lo < hi) { int mid = (lo + hi) >> 1; if (batch[mid] < b) lo = mid + 1; else hi = mid; }
    int seg_lo = lo;
    lo = 0; hi = n;
    while (lo < hi) { int mid = (lo + hi) >> 1; if (batch[mid] < b + 1) lo = mid + 1; else hi = mid; }
    float cnt = (float)(lo - seg_lo);
    if (cnt < 1.f) cnt = 1.f;
    float v = (sums[b * 64 + lane] / cnt) * wr[lane];
#pragma unroll
    for (int off = 32; off; off >>= 1) v += __shfl_xor(v, off);
    if (lane == 0) out[b] = v + br[0];
}

// ---------------------------------------------------------------------------
extern "C" void kernel_launch(void* const* d_in, const int* in_sizes, int n_in,
                              void* d_out, int out_size, void* d_ws, size_t ws_size,
                              hipStream_t stream) {
    const float* x   = (const float*)d_in[0];
    const int*   ei  = (const int*)d_in[1];
    const int*   bat = (const int*)d_in[2];
    const float* W1  = (const float*)d_in[3];
    const float* as1 = (const float*)d_in[4];
    const float* ad1 = (const float*)d_in[5];
    const float* b1  = (const float*)d_in[6];
    const float* W2  = (const float*)d_in[7];
    const float* as2 = (const float*)d_in[8];
    const float* ad2 = (const float*)d_in[9];
    const float* b2  = (const float*)d_in[10];
    const float* W3  = (const float*)d_in[11];
    const float* as3 = (const float*)d_in[12];
    const float* ad3 = (const float*)d_in[13];
    const float* b3  = (const float*)d_in[14];
    const float* wp  = (const float*)d_in[15];
    const float* bp  = (const float*)d_in[16];
    const float* wr  = (const float*)d_in[17];
    const float* br  = (const float*)d_in[18];
    float* out = (float*)d_out;

    const int N    = in_sizes[2];          // 20000
    const int E    = in_sizes[1] / 2;      // 320000
    const int DIN  = in_sizes[0] / N;      // 128
    const int Etot = E + N;
    const int Bc   = out_size;             // 16

    char* ws = (char*)d_ws;
    size_t off = 0;
    auto alloc = [&](size_t bytes) {
        void* p = ws + off;
        off = (off + bytes + 255) & ~(size_t)255;
        return p;
    };
    int*   deg    = (int*)alloc((size_t)N * 4);
    int*   rowptr = (int*)alloc((size_t)(N + 1) * 4);
    int*   cursor = (int*)alloc((size_t)N * 4);
    int*   bsum   = (int*)alloc((size_t)1024 * 4);
    int*   srcs   = (int*)alloc((size_t)Etot * 4);
    float* bufA   = (float*)alloc((size_t)N * 256 * 4);     // GEMM out h (head-major)
    u16*   Ahi    = (u16*)alloc((size_t)N * 256 * 2);       // x/g split hi
    u16*   Alo    = (u16*)alloc((size_t)N * 256 * 2);       // x/g split lo
    float* h3     = (float*)alloc((size_t)N * 64 * 4);
    float* g3     = (float*)alloc((size_t)N * 64 * 4);
    float* esrc   = (float*)alloc((size_t)N * 4 * 4);
    float* edst   = (float*)alloc((size_t)N * 4 * 4);
    float* attn   = (float*)alloc((size_t)N * 4);
    float* sums   = (float*)alloc((size_t)Bc * 64 * 4);
    u16*   w1hi   = (u16*)alloc((size_t)256 * DIN * 2);
    u16*   w1lo   = (u16*)alloc((size_t)256 * DIN * 2);
    u16*   w2hi   = (u16*)alloc((size_t)256 * 256 * 2);
    u16*   w2lo   = (u16*)alloc((size_t)256 * 256 * 2);
    u16*   w3hi   = (u16*)alloc((size_t)64 * 256 * 2);
    u16*   w3lo   = (u16*)alloc((size_t)64 * 256 * 2);
    (void)ws_size;

    // CSR build (shared by all layers); hierarchical parallel scan
    hipMemsetAsync(deg, 0, (size_t)N * 4, stream);
    int eb = (Etot + 255) / 256;
    int nb = (N + 255) / 256;              // 79 blocks <= 1024
    edge_hist_k<<<eb, 256, 0, stream>>>(ei, E, N, deg);
    scan_p1_k<<<nb, 256, 0, stream>>>(deg, bsum, N);
    scan_p2_k<<<1, 1024, 0, stream>>>(bsum, nb);
    scan_p3_k<<<nb, 256, 0, stream>>>(deg, bsum, rowptr, cursor, N);
    edge_scatter_k<<<eb, 256, 0, stream>>>(ei, E, N, cursor, srcs);

    // weight splits (transposed) + x split
    splitT_bf16_k<<<(DIN * 256 + 255) / 256, 256, 0, stream>>>(W1, w1hi, w1lo, DIN, 256);
    splitT_bf16_k<<<(256 * 256 + 255) / 256, 256, 0, stream>>>(W2, w2hi, w2lo, 256, 256);
    splitT_bf16_k<<<(256 * 64 + 255) / 256, 256, 0, stream>>>(W3, w3hi, w3lo, 256, 64);
    split_bf16_k<<<(N * DIN / 4 + 255) / 256, 256, 0, stream>>>(x, Ahi, Alo, N * DIN / 4);

    const int mb = (N + 63) / 64;          // 313
    int nb4 = (N + 3) / 4;
    dim3 agg_grid(nb4, 4);

    // Layer 1: DIN -> (4,64) concat      (BN=128 -> 2 n-tiles)
    gemm_lds_k<2><<<mb * 2, 256, 0, stream>>>(Ahi, Alo, w1hi, w1lo, bufA, as1, ad1, esrc, edst, N, 256, DIN);
    gat_aggregate_hm_k<<<agg_grid, 256, 0, stream>>>(bufA, esrc, edst, rowptr, srcs, b1, Ahi, Alo, N);

    // Layer 2: 256 -> (4,64) concat
    gemm_lds_k<2><<<mb * 2, 256, 0, stream>>>(Ahi, Alo, w2hi, w2lo, bufA, as2, ad2, esrc, edst, N, 256, 256);
    gat_aggregate_hm_k<<<agg_grid, 256, 0, stream>>>(bufA, esrc, edst, rowptr, srcs, b2, Ahi, Alo, N);

    // Layer 3: 256 -> (1,64) mean + fused node-attention gate   (BN=64)
    gemm_lds_k<1><<<mb, 256, 0, stream>>>(Ahi, Alo, w3hi, w3lo, h3, as3, ad3, esrc, edst, N, 64, 256);
    gat_aggregate1_attn_k<<<nb4, 256, 0, stream>>>(h3, esrc, edst, rowptr, srcs, b3, wp, bp, g3, attn, N);

    // Attention pool + regressor (parallel)
    hipMemsetAsync(sums, 0, (size_t)Bc * 64 * 4, stream);
    pool_partial_k<<<256, 256, 0, stream>>>(g3, attn, bat, N, sums);
    regress_k<<<1, 1024, 0, stream>>>(sums, bat, N, wr, br, out, Bc);
}

// Round 14
// 245.723 us; speedup vs baseline: 1.6762x; 1.0215x over previous
//
#include <hip/hip_runtime.h>

// ---------------------------------------------------------------------------
// GAT (3 layers) + attention pooling + regressor.
// GEMMs: split-bf16 MFMA (a_hi+a_lo, 3 products, f32 accum), A staged in LDS
// via global_load_lds; attn scores fused into GEMM epilogue; h stored
// HEAD-MAJOR [H][N][64] (5.1MB/head gather set).
// Aggregates: latency-overlapped — src published to LDS first, ALL row loads
// issued before the weight phase (gathers overlap exp/reduce), 4-edge static
// steps with w=0 padding (no clamps in hot path).
// N=20000 nodes, E=320000 edges (+N self loops), H=4 heads, C=64, B=16 graphs.
// ---------------------------------------------------------------------------

typedef unsigned short u16;
typedef __attribute__((ext_vector_type(8))) short bf16x8;
typedef __attribute__((ext_vector_type(4))) float f32x4;

__device__ __forceinline__ u16 bf16rn(float x) {
    unsigned u = __float_as_uint(x);
    u += 0x7FFFu + ((u >> 16) & 1u);
    return (u16)(u >> 16);
}
__device__ __forceinline__ float bf16f(u16 h) {
    return __uint_as_float(((unsigned)h) << 16);
}

__device__ __forceinline__ void gload16(const u16* g, u16* l) {
    __builtin_amdgcn_global_load_lds(
        (const __attribute__((address_space(1))) unsigned int*)g,
        (__attribute__((address_space(3))) unsigned int*)l, 16, 0, 0);
}

// ---------------- CSR-by-destination build ----------------
__global__ void edge_hist_k(const int* __restrict__ ei, int E, int n, int* __restrict__ deg) {
    int i = blockIdx.x * blockDim.x + threadIdx.x;
    if (i >= E + n) return;
    int dst = (i < E) ? ei[E + i] : (i - E);   // self-loop for i >= E
    atomicAdd(&deg[dst], 1);
}

// 3-pass hierarchical exclusive scan
__global__ void scan_p1_k(const int* __restrict__ deg, int* __restrict__ bsum, int n) {
    __shared__ int red[256];
    int tid = threadIdx.x;
    int i = blockIdx.x * 256 + tid;
    int v = (i < n) ? deg[i] : 0;
    red[tid] = v;
    __syncthreads();
    for (int off = 128; off; off >>= 1) {
        if (tid < off) red[tid] += red[tid + off];
        __syncthreads();
    }
    if (tid == 0) bsum[blockIdx.x] = red[0];
}

__global__ __launch_bounds__(1024) void scan_p2_k(int* __restrict__ bsum, int nb) {
    __shared__ int part[1024];
    int tid = threadIdx.x;
    int v = (tid < nb) ? bsum[tid] : 0;
    part[tid] = v;
    __syncthreads();
    for (int off = 1; off < 1024; off <<= 1) {
        int t = (tid >= off) ? part[tid - off] : 0;
        __syncthreads();
        part[tid] += t;
        __syncthreads();
    }
    if (tid < nb) bsum[tid] = part[tid] - v;      // exclusive
}

__global__ void scan_p3_k(const int* __restrict__ deg, const int* __restrict__ bsum,
                          int* __restrict__ rowptr, int* __restrict__ cursor, int n) {
    __shared__ int part[256];
    int tid = threadIdx.x;
    int i = blockIdx.x * 256 + tid;
    int v = (i < n) ? deg[i] : 0;
    part[tid] = v;
    __syncthreads();
    for (int off = 1; off < 256; off <<= 1) {
        int t = (tid >= off) ? part[tid - off] : 0;
        __syncthreads();
        part[tid] += t;
        __syncthreads();
    }
    int excl = part[tid] - v + bsum[blockIdx.x];
    if (i < n) { rowptr[i] = excl; cursor[i] = excl; }
    if (i == n - 1) rowptr[n] = excl + v;
}

__global__ void edge_scatter_k(const int* __restrict__ ei, int E, int n,
                               int* __restrict__ cursor, int* __restrict__ srcs) {
    int i = blockIdx.x * blockDim.x + threadIdx.x;
    if (i >= E + n) return;
    int src, dst;
    if (i < E) { src = ei[i]; dst = ei[E + i]; }
    else       { src = i - E; dst = src; }
    int pos = atomicAdd(&cursor[dst], 1);
    srcs[pos] = src;
}

// ---------------- bf16 split conversions ----------------
__global__ void split_bf16_k(const float* __restrict__ in, u16* __restrict__ hi,
                             u16* __restrict__ lo, int n4) {
    int i = blockIdx.x * 256 + threadIdx.x;
    if (i >= n4) return;
    float4 v = reinterpret_cast<const float4*>(in)[i];
    u16 hx = bf16rn(v.x), hy = bf16rn(v.y), hz = bf16rn(v.z), hw = bf16rn(v.w);
    ushort4 H = make_ushort4(hx, hy, hz, hw);
    ushort4 L = make_ushort4(bf16rn(v.x - bf16f(hx)), bf16rn(v.y - bf16f(hy)),
                             bf16rn(v.z - bf16f(hz)), bf16rn(v.w - bf16f(hw)));
    reinterpret_cast<ushort4*>(hi)[i] = H;
    reinterpret_cast<ushort4*>(lo)[i] = L;
}

// W[K][Nn] row-major -> transposed split Wt[Nn][K] (hi, lo)
__global__ void splitT_bf16_k(const float* __restrict__ W, u16* __restrict__ thi,
                              u16* __restrict__ tlo, int K, int Nn) {
    int idx = blockIdx.x * 256 + threadIdx.x;
    if (idx >= K * Nn) return;
    int k = idx / Nn, nn = idx - k * Nn;
    float v = W[idx];
    u16 h = bf16rn(v);
    u16 l = bf16rn(v - bf16f(h));
    thi[(size_t)nn * K + k] = h;
    tlo[(size_t)nn * K + k] = l;
}

// ---------------- split-bf16 MFMA GEMM, LDS-staged A, fused attn scores ----
// C emitted HEAD-MAJOR: C[((col>>6)*M + row)*64 + (col&63)].
// Epilogue also emits esrc/edst [M][Nn/64]: per-row dot with a_src/a_dst.
template <int NF>
__global__ __launch_bounds__(256) void gemm_lds_k(
        const u16* __restrict__ Ahi, const u16* __restrict__ Alo,
        const u16* __restrict__ Bthi, const u16* __restrict__ Btlo,
        float* __restrict__ C,
        const float* __restrict__ a_src, const float* __restrict__ a_dst,
        float* __restrict__ esrc, float* __restrict__ edst,
        int M, int Nn, int K) {
    __shared__ u16 Ah[2][4][64 * 8];   // [buf][kg][row*8]
    __shared__ u16 Al[2][4][64 * 8];
    const int mb = (M + 63) >> 6;
    const int mi = blockIdx.x % mb;
    const int ni = blockIdx.x / mb;
    const int m0 = mi * 64;
    const int n0 = ni * (NF * 64);
    const int tid = threadIdx.x;
    const int wv = tid >> 6;
    const int lane = tid & 63;
    const int rr = lane & 15;
    const int kg = lane >> 4;

    int srow = m0 + lane; if (srow > M - 1) srow = M - 1;
    const u16* sh = Ahi + (size_t)srow * K + wv * 8;
    const u16* sl = Alo + (size_t)srow * K + wv * 8;

    const u16* pbh[NF];
    const u16* pbl[NF];
#pragma unroll
    for (int nf = 0; nf < NF; ++nf) {
        int col = n0 + (wv * NF + nf) * 16 + rr;
        pbh[nf] = Bthi + (size_t)col * K + kg * 8;
        pbl[nf] = Btlo + (size_t)col * K + kg * 8;
    }

    f32x4 acc[4][NF];
#pragma unroll
    for (int mf = 0; mf < 4; ++mf)
#pragma unroll
        for (int nf = 0; nf < NF; ++nf) acc[mf][nf] = (f32x4){0.f, 0.f, 0.f, 0.f};

    bf16x8 bhc[NF], blc[NF], bhn[NF], bln[NF];
#pragma unroll
    for (int nf = 0; nf < NF; ++nf) {
        bhc[nf] = *reinterpret_cast<const bf16x8*>(pbh[nf]);
        blc[nf] = *reinterpret_cast<const bf16x8*>(pbl[nf]);
    }
    gload16(sh, &Ah[0][wv][0]);
    gload16(sl, &Al[0][wv][0]);
    __syncthreads();

    const int NT = K >> 5;
    for (int t = 0; t < NT; ++t) {
        const int cur = t & 1;
        if (t + 1 < NT) {
            const int kc = (t + 1) << 5;
#pragma unroll
            for (int nf = 0; nf < NF; ++nf) {
                bhn[nf] = *reinterpret_cast<const bf16x8*>(pbh[nf] + kc);
                bln[nf] = *reinterpret_cast<const bf16x8*>(pbl[nf] + kc);
            }
            gload16(sh + kc, &Ah[cur ^ 1][wv][0]);
            gload16(sl + kc, &Al[cur ^ 1][wv][0]);
        }
        bf16x8 ah[4], al[4];
#pragma unroll
        for (int mf = 0; mf < 4; ++mf) {
            ah[mf] = *reinterpret_cast<const bf16x8*>(&Ah[cur][kg][(mf * 16 + rr) * 8]);
            al[mf] = *reinterpret_cast<const bf16x8*>(&Al[cur][kg][(mf * 16 + rr) * 8]);
        }
#pragma unroll
        for (int mf = 0; mf < 4; ++mf)
#pragma unroll
            for (int nf = 0; nf < NF; ++nf) {
                acc[mf][nf] = __builtin_amdgcn_mfma_f32_16x16x32_bf16(ah[mf], bhc[nf], acc[mf][nf], 0, 0, 0);
                acc[mf][nf] = __builtin_amdgcn_mfma_f32_16x16x32_bf16(ah[mf], blc[nf], acc[mf][nf], 0, 0, 0);
                acc[mf][nf] = __builtin_amdgcn_mfma_f32_16x16x32_bf16(al[mf], bhc[nf], acc[mf][nf], 0, 0, 0);
            }
#pragma unroll
        for (int nf = 0; nf < NF; ++nf) { bhc[nf] = bhn[nf]; blc[nf] = bln[nf]; }
        __syncthreads();
    }

    // ---- C store (head-major) ----
#pragma unroll
    for (int mf = 0; mf < 4; ++mf)
#pragma unroll
        for (int nf = 0; nf < NF; ++nf) {
            int col = n0 + (wv * NF + nf) * 16 + rr;
            float* cb = C + ((size_t)(col >> 6) * M) * 64 + (col & 63);
#pragma unroll
            for (int rg = 0; rg < 4; ++rg) {
                int row = m0 + mf * 16 + kg * 4 + rg;
                if (row < M) cb[(size_t)row * 64] = acc[mf][nf][rg];
            }
        }

    // ---- fused attention scores: per-row dot with a_src / a_dst ----
    float asv[NF], adv[NF];
#pragma unroll
    for (int nf = 0; nf < NF; ++nf) {
        int col = n0 + (wv * NF + nf) * 16 + rr;
        asv[nf] = a_src[col];
        adv[nf] = a_dst[col];
    }
    float ps[4][4], pd[4][4];   // [mf][rg]
#pragma unroll
    for (int mf = 0; mf < 4; ++mf)
#pragma unroll
        for (int rg = 0; rg < 4; ++rg) {
            float s = 0.f, dvv = 0.f;
#pragma unroll
            for (int nf = 0; nf < NF; ++nf) {
                s = fmaf(acc[mf][nf][rg], asv[nf], s);
                dvv = fmaf(acc[mf][nf][rg], adv[nf], dvv);
            }
#pragma unroll
            for (int off = 1; off < 16; off <<= 1) {
                s += __shfl_xor(s, off);
                dvv += __shfl_xor(dvv, off);
            }
            ps[mf][rg] = s;
            pd[mf][rg] = dvv;
        }
    // cross-wave combine via LDS (reuse Ah; all reads of it completed)
    float* sm_src = (float*)&Ah[0][0][0];     // [4 waves][64 rows]
    float* sm_dst = sm_src + 256;
    if (rr == 0) {
#pragma unroll
        for (int mf = 0; mf < 4; ++mf)
#pragma unroll
            for (int rg = 0; rg < 4; ++rg) {
                int rl = mf * 16 + kg * 4 + rg;
                sm_src[wv * 64 + rl] = ps[mf][rg];
                sm_dst[wv * 64 + rl] = pd[mf][rg];
            }
    }
    __syncthreads();
    if (tid < 64) {
        int row = m0 + tid;
        if (row < M) {
            const int HTOT = Nn >> 6;
            constexpr int WPH = 4 / NF;        // waves per head
#pragma unroll
            for (int hl = 0; hl < NF; ++hl) {
                float es = 0.f, edv = 0.f;
#pragma unroll
                for (int w = 0; w < WPH; ++w) {
                    es += sm_src[(hl * WPH + w) * 64 + tid];
                    edv += sm_dst[(hl * WPH + w) * 64 + tid];
                }
                int hg = ni * NF + hl;
                esrc[(size_t)row * HTOT + hg] = es;
                edst[(size_t)row * HTOT + hg] = edv;
            }
        }
    }
}

// ---------------- GAT aggregation, head-split, latency-overlapped ----------
// Wave per (dst,head); lane = (es=lane>>4, cq=lane&15). Per 64-edge chunk:
// publish src to LDS, issue ALL row loads (up to 16, covering 64 slots),
// THEN weight phase (overlaps gathers). Padded lanes wrote w=0 -> static
// 4-edge STEPs need no clamps.
#define AGG_STEP(K, RK)                                                        \
    if (cnt > 4 * K) {                                                         \
        float wk = __int_as_float(swv[4 * K + es].y);                          \
        acc.x = fmaf(wk, RK.x, acc.x); acc.y = fmaf(wk, RK.y, acc.y);          \
        acc.z = fmaf(wk, RK.z, acc.z); acc.w = fmaf(wk, RK.w, acc.w);          \
    }

__global__ __launch_bounds__(256) void gat_aggregate_hm_k(
        const float* __restrict__ hm, const float* __restrict__ esrc,
        const float* __restrict__ edst, const int* __restrict__ rowptr,
        const int* __restrict__ srcs, const float* __restrict__ bias,
        u16* __restrict__ ghi, u16* __restrict__ glo, int n) {
    __shared__ int2 swb[4][64];
    int wv = threadIdx.x >> 6;
    int d = blockIdx.x * 4 + wv;
    int lane = threadIdx.x & 63;
    int hh = blockIdx.y;                        // head
    if (d >= n) return;
    const float* hbase = hm + (size_t)hh * n * 64;
    const int es = lane >> 4;                   // edge sub-slot 0..3
    const int cq = lane & 15;                   // channel quad
    int2* swv = swb[wv];
    float ed = edst[d * 4 + hh];
    int lo = rowptr[d], hi = rowptr[d + 1];
    float4 acc = make_float4(0.f, 0.f, 0.f, 0.f);
    float den = 0.f;
    for (int base = lo; base < hi; base += 64) {
        int cnt = min(64, hi - base);
        int idx = base + lane;
        int s = srcs[(idx < hi) ? idx : lo];
        swv[lane].x = s;                        // publish src EARLY (same-wave LDS)
        auto ROWL = [&](int j) -> float4 {      // j < 64 always valid (padded s ok)
            int sp = swv[j].x;
            return *reinterpret_cast<const float4*>(&hbase[(size_t)sp * 64 + cq * 4]);
        };
        float4 z = make_float4(0.f, 0.f, 0.f, 0.f);
        float4 r0 = z, r1 = z, r2 = z, r3 = z, r4 = z, r5 = z, r6 = z, r7 = z;
        // issue all row loads BEFORE the weight phase (gathers overlap exp/reduce)
        r0 = ROWL(es);
        if (cnt > 4)  r1 = ROWL(4 + es);
        if (cnt > 8)  r2 = ROWL(8 + es);
        if (cnt > 12) r3 = ROWL(12 + es);
        if (cnt > 16) r4 = ROWL(16 + es);
        if (cnt > 20) r5 = ROWL(20 + es);
        if (cnt > 24) r6 = ROWL(24 + es);
        if (cnt > 28) r7 = ROWL(28 + es);
        // weight phase (overlaps in-flight gathers)
        float e = esrc[s * 4 + hh] + ed;
        e = (e >= 0.f) ? e : 0.2f * e;          // leaky_relu(0.2)
        float w = (lane < cnt) ? __expf(e) : 0.f;
        float ws = w;
#pragma unroll
        for (int off = 1; off < 64; off <<= 1) ws += __shfl_xor(ws, off);
        den += ws;
        swv[lane].y = __float_as_int(w);        // padded lanes publish w=0
        AGG_STEP(0, r0) AGG_STEP(1, r1) AGG_STEP(2, r2) AGG_STEP(3, r3)
        AGG_STEP(4, r4) AGG_STEP(5, r5) AGG_STEP(6, r6) AGG_STEP(7, r7)
        if (cnt > 32) {                         // rare (deg>32)
            r0 = ROWL(32 + es);
            if (cnt > 36) r1 = ROWL(36 + es);
            if (cnt > 40) r2 = ROWL(40 + es);
            if (cnt > 44) r3 = ROWL(44 + es);
            if (cnt > 48) r4 = ROWL(48 + es);
            if (cnt > 52) r5 = ROWL(52 + es);
            if (cnt > 56) r6 = ROWL(56 + es);
            if (cnt > 60) r7 = ROWL(60 + es);
            AGG_STEP(8, r0)  AGG_STEP(9, r1)  AGG_STEP(10, r2) AGG_STEP(11, r3)
            AGG_STEP(12, r4) AGG_STEP(13, r5) AGG_STEP(14, r6) AGG_STEP(15, r7)
        }
    }
    // combine the 4 edge sub-slots (lanes differing in bits 4,5)
    acc.x += __shfl_xor(acc.x, 16); acc.x += __shfl_xor(acc.x, 32);
    acc.y += __shfl_xor(acc.y, 16); acc.y += __shfl_xor(acc.y, 32);
    acc.z += __shfl_xor(acc.z, 16); acc.z += __shfl_xor(acc.z, 32);
    acc.w += __shfl_xor(acc.w, 16); acc.w += __shfl_xor(acc.w, 32);
    if (es == 0) {
        int c0 = hh * 64 + cq * 4;
        float inv = 1.f / den;
        float4 bv = *reinterpret_cast<const float4*>(&bias[c0]);
        float4 o;
        o.x = acc.x * inv + bv.x;
        o.y = acc.y * inv + bv.y;
        o.z = acc.z * inv + bv.z;
        o.w = acc.w * inv + bv.w;
        o.x = (o.x > 0.f) ? o.x : expm1f(o.x);   // ELU
        o.y = (o.y > 0.f) ? o.y : expm1f(o.y);
        o.z = (o.z > 0.f) ? o.z : expm1f(o.z);
        o.w = (o.w > 0.f) ? o.w : expm1f(o.w);
        u16 hx = bf16rn(o.x), hy = bf16rn(o.y), hz = bf16rn(o.z), hw = bf16rn(o.w);
        ushort4 H = make_ushort4(hx, hy, hz, hw);
        ushort4 L = make_ushort4(bf16rn(o.x - bf16f(hx)), bf16rn(o.y - bf16f(hy)),
                                 bf16rn(o.z - bf16f(hz)), bf16rn(o.w - bf16f(hw)));
        *reinterpret_cast<ushort4*>(&ghi[(size_t)d * 256 + c0]) = H;
        *reinterpret_cast<ushort4*>(&glo[(size_t)d * 256 + c0]) = L;
    }
}

// ---------------- layer-3 aggregate (1 head) fused with node attn gate ------
__global__ __launch_bounds__(256) void gat_aggregate1_attn_k(
        const float* __restrict__ hin, const float* __restrict__ esrc,
        const float* __restrict__ edst, const int* __restrict__ rowptr,
        const int* __restrict__ srcs, const float* __restrict__ bias,
        const float* __restrict__ wp, const float* __restrict__ bp,
        float* __restrict__ gout, float* __restrict__ attn, int n) {
    __shared__ int2 swb[4][64];
    int wv = threadIdx.x >> 6;
    int d = blockIdx.x * 4 + wv;
    int lane = threadIdx.x & 63;
    if (d >= n) return;
    const int es = lane >> 4;
    const int cq = lane & 15;
    int2* swv = swb[wv];
    float ed = edst[d];
    int lo = rowptr[d], hi = rowptr[d + 1];
    float4 acc = make_float4(0.f, 0.f, 0.f, 0.f);
    float den = 0.f;
    for (int base = lo; base < hi; base += 64) {
        int cnt = min(64, hi - base);
        int idx = base + lane;
        int s = srcs[(idx < hi) ? idx : lo];
        swv[lane].x = s;
        auto ROWL = [&](int j) -> float4 {
            int sp = swv[j].x;
            return *reinterpret_cast<const float4*>(&hin[(size_t)sp * 64 + cq * 4]);
        };
        float4 z = make_float4(0.f, 0.f, 0.f, 0.f);
        float4 r0 = z, r1 = z, r2 = z, r3 = z, r4 = z, r5 = z, r6 = z, r7 = z;
        r0 = ROWL(es);
        if (cnt > 4)  r1 = ROWL(4 + es);
        if (cnt > 8)  r2 = ROWL(8 + es);
        if (cnt > 12) r3 = ROWL(12 + es);
        if (cnt > 16) r4 = ROWL(16 + es);
        if (cnt > 20) r5 = ROWL(20 + es);
        if (cnt > 24) r6 = ROWL(24 + es);
        if (cnt > 28) r7 = ROWL(28 + es);
        float e = esrc[s] + ed;
        e = (e >= 0.f) ? e : 0.2f * e;
        float w = (lane < cnt) ? __expf(e) : 0.f;
        float ws = w;
#pragma unroll
        for (int off = 1; off < 64; off <<= 1) ws += __shfl_xor(ws, off);
        den += ws;
        swv[lane].y = __float_as_int(w);
        AGG_STEP(0, r0) AGG_STEP(1, r1) AGG_STEP(2, r2) AGG_STEP(3, r3)
        AGG_STEP(4, r4) AGG_STEP(5, r5) AGG_STEP(6, r6) AGG_STEP(7, r7)
        if (cnt > 32) {
            r0 = ROWL(32 + es);
            if (cnt > 36) r1 = ROWL(36 + es);
            if (cnt > 40) r2 = ROWL(40 + es);
            if (cnt > 44) r3 = ROWL(44 + es);
            if (cnt > 48) r4 = ROWL(48 + es);
            if (cnt > 52) r5 = ROWL(52 + es);
            if (cnt > 56) r6 = ROWL(56 + es);
            if (cnt > 60) r7 = ROWL(60 + es);
            AGG_STEP(8, r0)  AGG_STEP(9, r1)  AGG_STEP(10, r2) AGG_STEP(11, r3)
            AGG_STEP(12, r4) AGG_STEP(13, r5) AGG_STEP(14, r6) AGG_STEP(15, r7)
        }
    }
    acc.x += __shfl_xor(acc.x, 16); acc.x += __shfl_xor(acc.x, 32);
    acc.y += __shfl_xor(acc.y, 16); acc.y += __shfl_xor(acc.y, 32);
    acc.z += __shfl_xor(acc.z, 16); acc.z += __shfl_xor(acc.z, 32);
    acc.w += __shfl_xor(acc.w, 16); acc.w += __shfl_xor(acc.w, 32);
    int c0 = cq * 4;
    float inv = 1.f / den;
    float4 bv = *reinterpret_cast<const float4*>(&bias[c0]);
    float4 o;
    o.x = acc.x * inv + bv.x;
    o.y = acc.y * inv + bv.y;
    o.z = acc.z * inv + bv.z;
    o.w = acc.w * inv + bv.w;
    o.x = (o.x > 0.f) ? o.x : expm1f(o.x);       // ELU
    o.y = (o.y > 0.f) ? o.y : expm1f(o.y);
    o.z = (o.z > 0.f) ? o.z : expm1f(o.z);
    o.w = (o.w > 0.f) ? o.w : expm1f(o.w);
    if (es == 0)
        *reinterpret_cast<float4*>(&gout[(size_t)d * 64 + c0]) = o;
    // node attention gate: full 64-ch dot (cq lanes each hold 4 channels)
    float4 wv4 = *reinterpret_cast<const float4*>(&wp[c0]);
    float v = o.x * wv4.x + o.y * wv4.y + o.z * wv4.z + o.w * wv4.w;
#pragma unroll
    for (int off = 1; off < 16; off <<= 1) v += __shfl_xor(v, off);
    if (lane == 0) attn[d] = 1.f / (1.f + __expf(-(v + bp[0])));
}

// ---------------- parallel segmented pooling (batch is sorted) --------------
__global__ void pool_partial_k(const float* __restrict__ g3, const float* __restrict__ attn,
                               const int* __restrict__ batch, int n, float* __restrict__ sums) {
    int wid = blockIdx.x * (blockDim.x >> 6) + (threadIdx.x >> 6);
    int lane = threadIdx.x & 63;
    int nwaves = gridDim.x * (blockDim.x >> 6);
    int per = (n + nwaves - 1) / nwaves;
    int i0 = wid * per;
    int i1 = i0 + per;
    if (i1 > n) i1 = n;
    if (i0 >= i1) return;
    int cur = batch[i0];
    float acc = 0.f;
    for (int i = i0; i < i1; ++i) {
        int b = batch[i];
        if (b != cur) {
            atomicAdd(&sums[cur * 64 + lane], acc);
            acc = 0.f;
            cur = b;
        }
        acc += g3[(size_t)i * 64 + lane] * attn[i];
    }
    atomicAdd(&sums[cur * 64 + lane], acc);
}

// ---------------- final regressor: one block, wave per graph ----------------
__global__ void regress_k(const float* __restrict__ sums, const int* __restrict__ batch, int n,
                          const float* __restrict__ wr, const float* __restrict__ br,
                          float* __restrict__ out, int B) {
    int b = threadIdx.x >> 6;
    int lane = threadIdx.x & 63;
    if (b >= B) return;
    int lo = 0, hi = n;
    while (lo < hi) { int mid = (lo + hi) >> 1; if (batch[mid] < b) lo = mid + 1; else hi = mid; }
    int seg_lo = lo;
    lo = 0; hi = n;
    while (lo < hi) { int mid = (lo + hi) >> 1; if (batch[mid] < b + 1) lo = mid + 1; else hi = mid; }
    float cnt = (float)(lo - seg_lo);
    if (cnt < 1.f) cnt = 1.f;
    float v = (sums[b * 64 + lane] / cnt) * wr[lane];
#pragma unroll
    for (int off = 32; off; off >>= 1) v += __shfl_xor(v, off);
    if (lane == 0) out[b] = v + br[0];
}

// ---------------------------------------------------------------------------
extern "C" void kernel_launch(void* const* d_in, const int* in_sizes, int n_in,
                              void* d_out, int out_size, void* d_ws, size_t ws_size,
                              hipStream_t stream) {
    const float* x   = (const float*)d_in[0];
    const int*   ei  = (const int*)d_in[1];
    const int*   bat = (const int*)d_in[2];
    const float* W1  = (const float*)d_in[3];
    const float* as1 = (const float*)d_in[4];
    const float* ad1 = (const float*)d_in[5];
    const float* b1  = (const float*)d_in[6];
    const float* W2  = (const float*)d_in[7];
    const float* as2 = (const float*)d_in[8];
    const float* ad2 = (const float*)d_in[9];
    const float* b2  = (const float*)d_in[10];
    const float* W3  = (const float*)d_in[11];
    const float* as3 = (const float*)d_in[12];
    const float* ad3 = (const float*)d_in[13];
    const float* b3  = (const float*)d_in[14];
    const float* wp  = (const float*)d_in[15];
    const float* bp  = (const float*)d_in[16];
    const float* wr  = (const float*)d_in[17];
    const float* br  = (const float*)d_in[18];
    float* out = (float*)d_out;

    const int N    = in_sizes[2];          // 20000
    const int E    = in_sizes[1] / 2;      // 320000
    const int DIN  = in_sizes[0] / N;      // 128
    const int Etot = E + N;
    const int Bc   = out_size;             // 16

    char* ws = (char*)d_ws;
    size_t off = 0;
    auto alloc = [&](size_t bytes) {
        void* p = ws + off;
        off = (off + bytes + 255) & ~(size_t)255;
        return p;
    };
    int*   deg    = (int*)alloc((size_t)N * 4);
    int*   rowptr = (int*)alloc((size_t)(N + 1) * 4);
    int*   cursor = (int*)alloc((size_t)N * 4);
    int*   bsum   = (int*)alloc((size_t)1024 * 4);
    int*   srcs   = (int*)alloc((size_t)Etot * 4);
    float* bufA   = (float*)alloc((size_t)N * 256 * 4);     // GEMM out h (head-major)
    u16*   Ahi    = (u16*)alloc((size_t)N * 256 * 2);       // x/g split hi
    u16*   Alo    = (u16*)alloc((size_t)N * 256 * 2);       // x/g split lo
    float* h3     = (float*)alloc((size_t)N * 64 * 4);
    float* g3     = (float*)alloc((size_t)N * 64 * 4);
    float* esrc   = (float*)alloc((size_t)N * 4 * 4);
    float* edst   = (float*)alloc((size_t)N * 4 * 4);
    float* attn   = (float*)alloc((size_t)N * 4);
    float* sums   = (float*)alloc((size_t)Bc * 64 * 4);
    u16*   w1hi   = (u16*)alloc((size_t)256 * DIN * 2);
    u16*   w1lo   = (u16*)alloc((size_t)256 * DIN * 2);
    u16*   w2hi   = (u16*)alloc((size_t)256 * 256 * 2);
    u16*   w2lo   = (u16*)alloc((size_t)256 * 256 * 2);
    u16*   w3hi   = (u16*)alloc((size_t)64 * 256 * 2);
    u16*   w3lo   = (u16*)alloc((size_t)64 * 256 * 2);
    (void)ws_size;

    // CSR build (shared by all layers); hierarchical parallel scan
    hipMemsetAsync(deg, 0, (size_t)N * 4, stream);
    int eb = (Etot + 255) / 256;
    int nb = (N + 255) / 256;              // 79 blocks <= 1024
    edge_hist_k<<<eb, 256, 0, stream>>>(ei, E, N, deg);
    scan_p1_k<<<nb, 256, 0, stream>>>(deg, bsum, N);
    scan_p2_k<<<1, 1024, 0, stream>>>(bsum, nb);
    scan_p3_k<<<nb, 256, 0, stream>>>(deg, bsum, rowptr, cursor, N);
    edge_scatter_k<<<eb, 256, 0, stream>>>(ei, E, N, cursor, srcs);

    // weight splits (transposed) + x split
    splitT_bf16_k<<<(DIN * 256 + 255) / 256, 256, 0, stream>>>(W1, w1hi, w1lo, DIN, 256);
    splitT_bf16_k<<<(256 * 256 + 255) / 256, 256, 0, stream>>>(W2, w2hi, w2lo, 256, 256);
    splitT_bf16_k<<<(256 * 64 + 255) / 256, 256, 0, stream>>>(W3, w3hi, w3lo, 256, 64);
    split_bf16_k<<<(N * DIN / 4 + 255) / 256, 256, 0, stream>>>(x, Ahi, Alo, N * DIN / 4);

    const int mb = (N + 63) / 64;          // 313
    int nb4 = (N + 3) / 4;
    dim3 agg_grid(nb4, 4);

    // Layer 1: DIN -> (4,64) concat      (BN=128 -> 2 n-tiles)
    gemm_lds_k<2><<<mb * 2, 256, 0, stream>>>(Ahi, Alo, w1hi, w1lo, bufA, as1, ad1, esrc, edst, N, 256, DIN);
    gat_aggregate_hm_k<<<agg_grid, 256, 0, stream>>>(bufA, esrc, edst, rowptr, srcs, b1, Ahi, Alo, N);

    // Layer 2: 256 -> (4,64) concat
    gemm_lds_k<2><<<mb * 2, 256, 0, stream>>>(Ahi, Alo, w2hi, w2lo, bufA, as2, ad2, esrc, edst, N, 256, 256);
    gat_aggregate_hm_k<<<agg_grid, 256, 0, stream>>>(bufA, esrc, edst, rowptr, srcs, b2, Ahi, Alo, N);

    // Layer 3: 256 -> (1,64) mean + fused node-attention gate   (BN=64)
    gemm_lds_k<1><<<mb, 256, 0, stream>>>(Ahi, Alo, w3hi, w3lo, h3, as3, ad3, esrc, edst, N, 64, 256);
    gat_aggregate1_attn_k<<<nb4, 256, 0, stream>>>(h3, esrc, edst, rowptr, srcs, b3, wp, bp, g3, attn, N);

    // Attention pool + regressor (parallel)
    hipMemsetAsync(sums, 0, (size_t)Bc * 64 * 4, stream);
    pool_partial_k<<<256, 256, 0, stream>>>(g3, attn, bat, N, sums);
    regress_k<<<1, 1024, 0, stream>>>(sums, bat, N, wr, br, out, Bc);
}